// Round 3
// baseline (115.462 us; speedup 1.0000x reference)
//
#include <hip/hip_runtime.h>
#include <cstdint>
#include <cstddef>

// ---------------------------------------------------------------------------
// Threefry-2x32, 20 rounds, key = threefry_seed(42) = (0, 42)  (JAX-exact;
// cipher hand-verified against Random123 KAT: key=(0,0),ctr=(0,0) ->
// 0x6b200159, 0x99ba4efe).
// ---------------------------------------------------------------------------
__device__ __forceinline__ uint32_t rotl32(uint32_t v, int d) {
  return (v << d) | (v >> (32 - d));
}

__device__ __forceinline__ void threefry2x32_seed42(uint32_t c0, uint32_t c1,
                                                    uint32_t& o0, uint32_t& o1) {
  const uint32_t ks0 = 0u;
  const uint32_t ks1 = 42u;
  const uint32_t ks2 = ks0 ^ ks1 ^ 0x1BD11BDAu;
  uint32_t x0 = c0 + ks0;
  uint32_t x1 = c1 + ks1;
#define TF_R(r) { x0 += x1; x1 = rotl32(x1, (r)); x1 ^= x0; }
  TF_R(13) TF_R(15) TF_R(26) TF_R(6)
  x0 += ks1; x1 += ks2 + 1u;
  TF_R(17) TF_R(29) TF_R(16) TF_R(24)
  x0 += ks2; x1 += ks0 + 2u;
  TF_R(13) TF_R(15) TF_R(26) TF_R(6)
  x0 += ks0; x1 += ks1 + 3u;
  TF_R(17) TF_R(29) TF_R(16) TF_R(24)
  x0 += ks1; x1 += ks2 + 4u;
  TF_R(13) TF_R(15) TF_R(26) TF_R(6)
  x0 += ks2; x1 += ks0 + 5u;
#undef TF_R
  o0 = x0; o1 = x1;
}

// JAX >= 0.5 default: jax_threefry_partitionable = True.
// Per flat element f (f < 2^32 here): counter = (hi, lo) = (0, f),
// 32-bit bits = o0 ^ o1  (XOR-fold of the 64-bit cipher output).
__device__ __forceinline__ uint32_t jax_random_bits32(uint32_t f) {
  uint32_t o0, o1;
  threefry2x32_seed42(0u, f, o0, o1);
  return o0 ^ o1;
}

// Gumbel g = -log(-log(u)) with fp32 rounding at each step (u fp32 exact JAX
// path; logs computed in f64 then rounded -> correctly-rounded fp32, ~XLA's).
__device__ __forceinline__ float gumbel_f(uint32_t f) {
  const uint32_t bits = jax_random_bits32(f);
  const float base = __uint_as_float((bits >> 9) | 0x3F800000u) - 1.0f;
  // u = max(minval, floats*(maxval-minval)+minval); (1.0-1e-10) rounds to 1.0f
  const float u = fmaxf(1e-10f, __fadd_rn(base, 1e-10f));
  const float w = (float)(-log((double)u));   // fp32-rounded -log(u)
  const float g = (float)(-log((double)w));   // fp32-rounded -log(w)
  return g;
}

// ---------------------------------------------------------------------------
// int64-vs-int32 edge_index detection (indices < 50000 -> int64 high words 0).
// ---------------------------------------------------------------------------
__global__ void detect_idx_dtype(const unsigned long long* __restrict__ buf,
                                 int n64, int* __restrict__ flag) {
  __shared__ int cnt;
  if (threadIdx.x == 0) cnt = 0;
  __syncthreads();
  if ((int)threadIdx.x < n64) {
    if ((buf[threadIdx.x] >> 32) != 0ull) atomicAdd(&cnt, 1);
  }
  __syncthreads();
  if (threadIdx.x == 0) *flag = (cnt * 2 < n64) ? 1 : 0;  // 1 => int64
}

// ---------------------------------------------------------------------------
// One thread per edge. Decision statistic replicates the reference fp32 path:
//   vf : strict sequential fp32 sum (XLA:CPU fusion-reduce order), no FMA
//   s0 = fl32(vf + g0); d = fl32(s0 - g1)
//   a=1 iff d >= 0, or softmax ties (fl32(exp(d)) >= 1 -> argmax picks idx 0)
// Output tolerance is 2e-2, so the sigmoids use ordinary math.
// ---------------------------------------------------------------------------
__global__ __launch_bounds__(256) void ipd_seq(
    const float* __restrict__ z1, const float* __restrict__ z2,
    const void* __restrict__ eidx, const int* __restrict__ flag64,
    float* __restrict__ out, int E, int D) {
  const long long e = (long long)blockIdx.x * blockDim.x + threadIdx.x;
  if (e >= E) return;
  const bool is64 = (*flag64 != 0);

  long long i0, i1;
  if (is64) {
    const long long* p = (const long long*)eidx;
    i0 = p[e]; i1 = p[E + e];
  } else {
    const int* p = (const int*)eidx;
    i0 = p[e]; i1 = p[E + e];
  }

  const float4* r0 = (const float4*)(z1 + (size_t)i0 * (size_t)D);
  const float4* r1 = (const float4*)(z1 + (size_t)i1 * (size_t)D);

  float acc = 0.0f;
  const int nt = D >> 2;
#pragma unroll 8
  for (int t = 0; t < nt; ++t) {
    const float4 x = r0[t];
    const float4 y = r1[t];
    acc = __fadd_rn(acc, __fmul_rn(x.x, y.x));
    acc = __fadd_rn(acc, __fmul_rn(x.y, y.y));
    acc = __fadd_rn(acc, __fmul_rn(x.z, y.z));
    acc = __fadd_rn(acc, __fmul_rn(x.w, y.w));
  }

  // Partitionable stream: flat indices 2e (col 0) and 2e+1 (col 1)
  const float g0 = gumbel_f(2u * (uint32_t)e);
  const float g1 = gumbel_f(2u * (uint32_t)e + 1u);

  const float s0 = __fadd_rn(acc, g0);   // (vf + g0) / tau, tau == 1
  const float d  = __fsub_rn(s0, g1);
  bool a = (d >= 0.0f);
  if (!a) {
    a = ((float)exp((double)d) >= 1.0f);  // softmax tie -> argmax 0 -> a=1
  }

  const float vn = __fadd_rn(z2[(size_t)i0 * 2], z2[(size_t)i1 * 2]);
  const float sf = 1.0f / (1.0f + expf(-acc));
  const float sn = 1.0f / (1.0f + expf(-vn));
  out[e] = a ? sf : sn;
}

// ---------------------------------------------------------------------------
extern "C" void kernel_launch(void* const* d_in, const int* in_sizes, int n_in,
                              void* d_out, int out_size, void* d_ws, size_t ws_size,
                              hipStream_t stream) {
  const float* z1  = (const float*)d_in[0];
  const float* z2  = (const float*)d_in[1];
  const void* eidx = d_in[2];
  // d_in[3] = temp (==1); tau > 0 does not change the hard argmax.

  const int E = in_sizes[2] / 2;
  const int N = in_sizes[1] / 2;
  const int D = in_sizes[0] / N;     // 128

  int* flag = (int*)d_ws;
  int n64 = E < 256 ? E : 256;
  hipLaunchKernelGGL(detect_idx_dtype, dim3(1), dim3(256), 0, stream,
                     (const unsigned long long*)eidx, n64, flag);

  const int threads = 256;
  const int blocks = (E + threads - 1) / threads;
  hipLaunchKernelGGL(ipd_seq, dim3(blocks), dim3(threads), 0, stream,
                     z1, z2, eidx, flag, (float*)d_out, E, D);
}